// Round 4
// baseline (144.013 us; speedup 1.0000x reference)
//
#include <hip/hip_runtime.h>

// Inv2d: B=4, C=128, H=W=64, G=8 (16 ch/grp), K=7, dil=2, pad=6,
// reduce 128->32, span 32->392.
//
// Round 4: R3's channel-split regressed (kv gen = 205M FMA is the BIGGER
// FLOP term; duplicating it x2 cost more than the occupancy gained).
//  - kv computed once per (px,g): thread owns all 16 channels.
//  - red_gen additionally writes x_t[b][p][128c] (channel-last) so the
//    apply phase loads 4 channels per float4: 196 VMEM insts/thread
//    instead of 784 -> 4x fewer latency stall points.
//  - kv generated row-by-row (kv[7] live) to keep VGPR ~90; row loads
//    are independent of row kv math -> VALU/VMEM overlap.

#define HW 4096   // 64*64
#define NC 128
#define NR 32
#define KK 49

__global__ __launch_bounds__(256) void red_gen(
    const float* __restrict__ x, const float* __restrict__ w_reduce,
    const float* __restrict__ b_reduce, float* __restrict__ red,
    float* __restrict__ x_t) {
  // grid: 256 blocks = b(4) x 64-px chunks(64). Block: 64 px, all 32 outs.
  __shared__ float xs[NC][64];       // 32 KB
  int t = threadIdx.x;
  int blk = blockIdx.x;
  int b = blk >> 6;
  int p0 = (blk & 63) * 64;

  // stage x[128 ch][64 px] -> LDS, float4-coalesced
  const float* xb = x + b * NC * HW + p0;
  int fx = t & 15;
  int c0 = t >> 4;
#pragma unroll
  for (int r = 0; r < 8; ++r) {
    int c = c0 + 16 * r;
    float4 v = *(const float4*)(xb + c * HW + fx * 4);
    *(float4*)(&xs[c][fx * 4]) = v;
  }
  __syncthreads();

  int px = t & 63;
  int quad = __builtin_amdgcn_readfirstlane(t >> 6);  // wave-uniform octet
  const float* wq = w_reduce + quad * 8 * NC;         // scalar (s_load) base

  float acc[8];
#pragma unroll
  for (int j = 0; j < 8; ++j) acc[j] = b_reduce[quad * 8 + j];

#pragma unroll 8
  for (int k = 0; k < NC; ++k) {
    float xk = xs[k][px];
#pragma unroll
    for (int j = 0; j < 8; ++j) acc[j] += xk * wq[j * NC + k];
  }

  float* rp = red + (b * NR + quad * 8) * HW + p0 + px;
#pragma unroll
  for (int j = 0; j < 8; ++j) rp[j * HW] = acc[j];

  // emit channel-last transpose x_t[b][p][128c] from the LDS tile.
  // lanes: px = t&63 consecutive -> xs[c][px] reads are conflict-free.
  float* xtb = x_t + ((size_t)(b * HW + p0 + px)) * NC;
  int cb2 = (t >> 6) * 32;
#pragma unroll
  for (int k = 0; k < 8; ++k) {
    int c = cb2 + k * 4;
    float4 v = make_float4(xs[c][px], xs[c + 1][px], xs[c + 2][px], xs[c + 3][px]);
    *(float4*)(xtb + c) = v;
  }
}

__global__ __launch_bounds__(256) void inv_apply(
    const float* __restrict__ x_t, const float* __restrict__ red,
    const float* __restrict__ w_span, const float* __restrict__ b_span,
    float* __restrict__ out) {
  // grid: 512 = pchunk(16) x g(8) x b(4); thread = 1 px, one group, 16 ch
  int blk = blockIdx.x;
  int pchunk = blk & 15;
  int g = (blk >> 4) & 7;
  int b = blk >> 7;
  int p = pchunk * 256 + threadIdx.x;
  int h = p >> 6, w = p & 63;

  // pixel's reduced features (coalesced)
  float r[NR];
  const float* rp = red + b * NR * HW + p;
#pragma unroll
  for (int o = 0; o < NR; ++o) r[o] = rp[o * HW];

  const float* xtg = x_t + ((size_t)b * HW) * NC + g * 16;
  float acc[16];
#pragma unroll
  for (int c = 0; c < 16; ++c) acc[c] = 0.f;

#pragma unroll
  for (int i = 0; i < 7; ++i) {
    int hh = h + 2 * i - 6;
    bool hv = (unsigned)hh < 64u;
    float kv[7];
    int off[7];
#pragma unroll
    for (int j = 0; j < 7; ++j) {
      int ww = w + 2 * j - 6;
      bool v = hv && ((unsigned)ww < 64u);
      int q = p + (2 * i - 6) * 64 + (2 * j - 6);
      q = min(max(q, 0), HW - 1);          // in-bounds; kv=0 kills garbage
      off[j] = q;
      const float* wrow = w_span + (g * KK + i * 7 + j) * NR;  // s_load
      float s0 = b_span[g * KK + i * 7 + j], s1 = 0.f;
#pragma unroll
      for (int o = 0; o < NR; o += 2) {
        s0 += r[o] * wrow[o];
        s1 += r[o + 1] * wrow[o + 1];
      }
      kv[j] = v ? (s0 + s1) : 0.f;
    }
#pragma unroll
    for (int j = 0; j < 7; ++j) {
      const float* xr = xtg + (size_t)off[j] * NC;
#pragma unroll
      for (int cq = 0; cq < 4; ++cq) {
        float4 xv = *(const float4*)(xr + cq * 4);
        acc[cq * 4 + 0] += xv.x * kv[j];
        acc[cq * 4 + 1] += xv.y * kv[j];
        acc[cq * 4 + 2] += xv.z * kv[j];
        acc[cq * 4 + 3] += xv.w * kv[j];
      }
    }
  }

  float* op = out + (b * NC + g * 16) * HW + p;
#pragma unroll
  for (int c = 0; c < 16; ++c) op[c * HW] = acc[c];
}

extern "C" void kernel_launch(void* const* d_in, const int* in_sizes, int n_in,
                              void* d_out, int out_size, void* d_ws, size_t ws_size,
                              hipStream_t stream) {
  const float* x        = (const float*)d_in[0];  // [4,128,64,64]
  const float* w_reduce = (const float*)d_in[1];  // [32,128]
  const float* b_reduce = (const float*)d_in[2];  // [32]
  const float* w_span   = (const float*)d_in[3];  // [392,32]
  const float* b_span   = (const float*)d_in[4];  // [392]
  float* out = (float*)d_out;                     // [4,128,64,64]

  float* red = (float*)d_ws;                      // [4,32,64,64]  = 2 MB
  float* x_t = (float*)d_ws + 4 * NR * HW;        // [4,4096,128]  = 8 MB

  red_gen<<<256, 256, 0, stream>>>(x, w_reduce, b_reduce, red, x_t);
  inv_apply<<<512, 256, 0, stream>>>(x_t, red, w_span, b_span, out);
}

// Round 5
// 125.017 us; speedup vs baseline: 1.1519x; 1.1519x over previous
//
#include <hip/hip_runtime.h>

// Inv2d: B=4, C=128, H=W=64, G=8 (16 ch/grp), K=7, dil=2, pad=6,
// reduce 128->32, span 32->392.
//
// Round 5: R4's channel-last x_t broke coalescing (64 lines/wave-load) ->
// reverted. New inv_apply: block = 4 px rows x 64 cols x 1 group. Stage the
// 16-row x 64-col x 16-ch halo window (exactly 64 KB) in LDS once
// (row-clamped at edges), then all 784 taps/thread are conflict-free
// ds_read_b32 (lane = col). Global element loads drop 12x; LDS-BW floor
// ~5 us chip-wide, kv-gen VALU (~4 us) overlaps on the VALU pipe.
// kv generated row-by-row (kv[7] live) so ds_reads interleave with kv FMA.

#define HW 4096   // 64*64
#define NC 128
#define NR 32
#define KK 49

__global__ __launch_bounds__(256) void red_gen(
    const float* __restrict__ x, const float* __restrict__ w_reduce,
    const float* __restrict__ b_reduce, float* __restrict__ red) {
  // grid: 256 blocks = b(4) x 64-px chunks(64). Block: 64 px, all 32 outs.
  __shared__ float xs[NC][64];       // 32 KB
  int t = threadIdx.x;
  int blk = blockIdx.x;
  int b = blk >> 6;
  int p0 = (blk & 63) * 64;

  const float* xb = x + b * NC * HW + p0;
  int fx = t & 15;
  int c0 = t >> 4;
#pragma unroll
  for (int r = 0; r < 8; ++r) {
    int c = c0 + 16 * r;
    float4 v = *(const float4*)(xb + c * HW + fx * 4);
    *(float4*)(&xs[c][fx * 4]) = v;
  }
  __syncthreads();

  int px = t & 63;
  int quad = __builtin_amdgcn_readfirstlane(t >> 6);  // wave-uniform octet
  const float* wq = w_reduce + quad * 8 * NC;         // scalar (s_load) base

  float acc[8];
#pragma unroll
  for (int j = 0; j < 8; ++j) acc[j] = b_reduce[quad * 8 + j];

#pragma unroll 8
  for (int k = 0; k < NC; ++k) {
    float xk = xs[k][px];
#pragma unroll
    for (int j = 0; j < 8; ++j) acc[j] += xk * wq[j * NC + k];
  }

  float* rp = red + (b * NR + quad * 8) * HW + p0 + px;
#pragma unroll
  for (int j = 0; j < 8; ++j) rp[j * HW] = acc[j];
}

__global__ __launch_bounds__(256) void inv_apply(
    const float* __restrict__ x, const float* __restrict__ red,
    const float* __restrict__ w_span, const float* __restrict__ b_span,
    float* __restrict__ out) {
  // grid: 512 = pchunk(16) x g(8) x b(4)
  // block: 256 thr = 4 px rows x 64 cols, one group (16 ch)
  // LDS: halo tile [ch=16][tile_row=16][col=64] = 64 KB
  __shared__ float xs[16][16][64];

  int t = threadIdx.x;
  int blk = blockIdx.x;
  int pchunk = blk & 15;
  int g = (blk >> 4) & 7;
  int b = blk >> 7;
  int p = pchunk * 256 + t;
  int h0 = pchunk * 4;               // first pixel row of block
  int hl = t >> 6;                   // local row 0..3 (wave-uniform)
  int h = h0 + hl;
  int w = t & 63;                    // col = lane

  // ---- stage halo tile: rows h0-6 .. h0+9 (content row-clamped) ----
  {
    int c = t >> 4;                  // channel 0..15
    int f4 = t & 15;                 // float4 index in 64-col row
    const float* xc = x + ((b * NC + g * 16 + c) * HW);
#pragma unroll
    for (int tr = 0; tr < 16; ++tr) {
      int sr = min(max(h0 - 6 + tr, 0), 63);
      float4 v = *(const float4*)(xc + sr * 64 + f4 * 4);
      *(float4*)(&xs[c][tr][f4 * 4]) = v;
    }
  }

  // pixel's reduced features (coalesced)
  float r[NR];
  const float* rp = red + b * NR * HW + p;
#pragma unroll
  for (int o = 0; o < NR; ++o) r[o] = rp[o * HW];

  __syncthreads();

  float acc[16];
#pragma unroll
  for (int c = 0; c < 16; ++c) acc[c] = 0.f;

#pragma unroll
  for (int i = 0; i < 7; ++i) {
    bool rowv = (unsigned)(h + 2 * i - 6) < 64u;
    int trow = hl + 2 * i;           // tile row (always in [0,16))
    float kv[7];
    int col[7];
#pragma unroll
    for (int j = 0; j < 7; ++j) {
      int ww = w + 2 * j - 6;
      bool v = rowv && ((unsigned)ww < 64u);
      col[j] = min(max(ww, 0), 63);
      const float* wrow = w_span + (g * KK + i * 7 + j) * NR;  // s_load
      float s0 = b_span[g * KK + i * 7 + j], s1 = 0.f;
#pragma unroll
      for (int o = 0; o < NR; o += 2) {
        s0 += r[o] * wrow[o];
        s1 += r[o + 1] * wrow[o + 1];
      }
      kv[j] = v ? (s0 + s1) : 0.f;
    }
#pragma unroll
    for (int c = 0; c < 16; ++c) {
#pragma unroll
      for (int j = 0; j < 7; ++j)
        acc[c] += xs[c][trow][col[j]] * kv[j];
    }
  }

  float* op = out + (b * NC + g * 16) * HW + p;
#pragma unroll
  for (int c = 0; c < 16; ++c) op[c * HW] = acc[c];
}

extern "C" void kernel_launch(void* const* d_in, const int* in_sizes, int n_in,
                              void* d_out, int out_size, void* d_ws, size_t ws_size,
                              hipStream_t stream) {
  const float* x        = (const float*)d_in[0];  // [4,128,64,64]
  const float* w_reduce = (const float*)d_in[1];  // [32,128]
  const float* b_reduce = (const float*)d_in[2];  // [32]
  const float* w_span   = (const float*)d_in[3];  // [392,32]
  const float* b_span   = (const float*)d_in[4];  // [392]
  float* out = (float*)d_out;                     // [4,128,64,64]

  float* red = (float*)d_ws;                      // [4,32,64,64] = 2 MB

  red_gen<<<256, 256, 0, stream>>>(x, w_reduce, b_reduce, red);
  inv_apply<<<512, 256, 0, stream>>>(x, red, w_span, b_span, out);
}

// Round 6
// 107.869 us; speedup vs baseline: 1.3351x; 1.1590x over previous
//
#include <hip/hip_runtime.h>

// Inv2d: B=4, C=128, H=W=64, G=8 (16 ch/grp), K=7, dil=2, pad=6,
// reduce 128->32, span 32->392.
//
// Round 6: R3/R5 showed fused kv-gen+apply is latency-bound (2400 serial
// ops/thread, 8 waves/CU, VALU 15%). Decouple into wave-rich kernels:
//   zero_pad: borders of x_pad[4][128][76][80] (= reference jnp.pad; all
//             boundary masking vanishes).
//   red_gen:  as before + writes x_pad interior (free stores).
//   ker_gen:  span GEMM -> ker[4][8][49][4096] in ws (L2-resident).
//             3584 blocks = 56 waves/CU, 256 FMA/thread.
//   inv_apply: thread = (1 ch, 4 px). kv row-slice (49x64) in LDS
//             (2-way bank + broadcast = free); per tap-row 5 float4
//             x_pad loads reused by 7 taps; 28 FMA. ~280 ops/thread,
//             16-24 waves/CU.

#define HW 4096   // 64*64
#define NC 128
#define NR 32
#define KK 49
#define PR 76     // padded rows (6+64+6)
#define PC 80     // padded cols (8+64+8, float4-aligned)

// ---------------------------------------------------------------- zero_pad
__global__ __launch_bounds__(256) void zero_pad(float* __restrict__ x_pad) {
  // grid 512 = (b*128+c); zero the 496 border float4s of one 76x80 plane
  float* base = x_pad + (size_t)blockIdx.x * PR * PC;
  int tid = threadIdx.x;
  float4 z = make_float4(0.f, 0.f, 0.f, 0.f);
#pragma unroll
  for (int r = 0; r < 2; ++r) {
    int idx = r * 256 + tid;
    if (idx < 496) {
      int d;
      if (idx < 120) d = idx;                       // rows 0..5
      else if (idx < 240) d = idx - 120 + 70 * 20;  // rows 70..75
      else {
        int k = idx - 240;                          // side cols, rows 6..69
        int row = 6 + (k >> 2);
        int c4 = k & 3;                             // -> col 0,4,72,76
        int col = (c4 < 2) ? c4 * 4 : 64 + c4 * 4;
        d = row * 20 + (col >> 2);
      }
      *(float4*)(base + d * 4) = z;
    }
  }
}

// ---------------------------------------------------------------- red_gen
__global__ __launch_bounds__(256) void red_gen(
    const float* __restrict__ x, const float* __restrict__ w_reduce,
    const float* __restrict__ b_reduce, float* __restrict__ red,
    float* __restrict__ x_pad) {
  // grid: 256 = b(4) x row(64). Block: one 64-px row, all 32 outputs.
  __shared__ float xs[NC][64];       // 32 KB
  int t = threadIdx.x;
  int blk = blockIdx.x;
  int b = blk >> 6;
  int row = blk & 63;
  int p0 = row * 64;

  const float* xb = x + b * NC * HW + p0;
  float* xpb = x_pad + ((size_t)(b * NC) * PR + (row + 6)) * PC + 8;
  int fx = t & 15;
  int c0 = t >> 4;
#pragma unroll
  for (int r = 0; r < 8; ++r) {
    int c = c0 + 16 * r;
    float4 v = *(const float4*)(xb + c * HW + fx * 4);
    *(float4*)(&xs[c][fx * 4]) = v;
    *(float4*)(xpb + (size_t)c * PR * PC + fx * 4) = v;  // x_pad interior
  }
  __syncthreads();

  int px = t & 63;
  int quad = __builtin_amdgcn_readfirstlane(t >> 6);  // wave-uniform octet
  const float* wq = w_reduce + quad * 8 * NC;         // scalar (s_load) base

  float acc[8];
#pragma unroll
  for (int j = 0; j < 8; ++j) acc[j] = b_reduce[quad * 8 + j];

#pragma unroll 8
  for (int k = 0; k < NC; ++k) {
    float xk = xs[k][px];
#pragma unroll
    for (int j = 0; j < 8; ++j) acc[j] += xk * wq[j * NC + k];
  }

  float* rp = red + (b * NR + quad * 8) * HW + p0 + px;
#pragma unroll
  for (int j = 0; j < 8; ++j) rp[j * HW] = acc[j];
}

// ---------------------------------------------------------------- ker_gen
__global__ __launch_bounds__(256) void ker_gen(
    const float* __restrict__ red, const float* __restrict__ w_span,
    const float* __restrict__ b_span, float* __restrict__ ker) {
  // grid: 3584 = pchunk(16) x i(7) x g(8) x b(4); thread: 7 taps, 1 px
  int blk = blockIdx.x;
  int pchunk = blk & 15;
  int t1 = blk >> 4;
  int i = t1 % 7;
  int t2 = t1 / 7;
  int g = t2 & 7;
  int b = t2 >> 3;
  int p = pchunk * 256 + threadIdx.x;

  float r[NR];
  const float* rp = red + b * NR * HW + p;
#pragma unroll
  for (int o = 0; o < NR; ++o) r[o] = rp[o * HW];

  float* kp = ker + ((size_t)((b * 8 + g) * KK + i * 7)) * HW + p;
#pragma unroll
  for (int j = 0; j < 7; ++j) {
    const float* wrow = w_span + (g * KK + i * 7 + j) * NR;  // s_load
    float s0 = b_span[g * KK + i * 7 + j], s1 = 0.f;
#pragma unroll
    for (int o = 0; o < NR; o += 2) {
      s0 += r[o] * wrow[o];
      s1 += r[o + 1] * wrow[o + 1];
    }
    kp[j * HW] = s0 + s1;
  }
}

// ---------------------------------------------------------------- inv_apply
__global__ __launch_bounds__(256) void inv_apply(
    const float* __restrict__ x_pad, const float* __restrict__ ker,
    float* __restrict__ out) {
  // grid: 2048 = h(64) x g(8) x b(4); block: 16 ch x 16 px-quads (1 row)
  __shared__ float kvs[KK * 64];     // this row's kernel slice, 12.25 KB
  int blk = blockIdx.x;
  int h = blk & 63;
  int g = (blk >> 6) & 7;
  int b = blk >> 9;
  int tid = threadIdx.x;
  int c = tid >> 4;                  // channel within group
  int l = tid & 15;                  // pixel quad (cols 4l..4l+3)

  // stage ker[b,g,:,h*64..h*64+63] -> LDS (coalesced 256B runs)
  const float* kerbg = ker + ((size_t)(b * 8 + g) * KK) * HW + h * 64;
#pragma unroll
  for (int r = 0; r < 13; ++r) {
    int idx = r * 256 + tid;
    if (idx < KK * 64) kvs[idx] = kerbg[(idx >> 6) * HW + (idx & 63)];
  }
  __syncthreads();

  const float* prow0 =
      x_pad + ((size_t)(b * NC + g * 16 + c) * PR + h) * PC;  // pad row h+2i
  float a0 = 0.f, a1 = 0.f, a2 = 0.f, a3 = 0.f;

#pragma unroll
  for (int i = 0; i < 7; ++i) {
    const float* pr = prow0 + 2 * i * PC + 4 * l;
    float xr[20];
#pragma unroll
    for (int m = 0; m < 5; ++m) {
      float4 v = *(const float4*)(pr + 4 * m);
      xr[4 * m] = v.x; xr[4 * m + 1] = v.y;
      xr[4 * m + 2] = v.z; xr[4 * m + 3] = v.w;
    }
#pragma unroll
    for (int j = 0; j < 7; ++j) {
      float4 kv = *(const float4*)(&kvs[(i * 7 + j) * 64 + 4 * l]);
      a0 += xr[2 * j + 2] * kv.x;
      a1 += xr[2 * j + 3] * kv.y;
      a2 += xr[2 * j + 4] * kv.z;
      a3 += xr[2 * j + 5] * kv.w;
    }
  }

  float* op = out + (size_t)(b * NC + g * 16 + c) * HW + h * 64 + 4 * l;
  *(float4*)op = make_float4(a0, a1, a2, a3);
}

extern "C" void kernel_launch(void* const* d_in, const int* in_sizes, int n_in,
                              void* d_out, int out_size, void* d_ws, size_t ws_size,
                              hipStream_t stream) {
  const float* x        = (const float*)d_in[0];  // [4,128,64,64]
  const float* w_reduce = (const float*)d_in[1];  // [32,128]
  const float* b_reduce = (const float*)d_in[2];  // [32]
  const float* w_span   = (const float*)d_in[3];  // [392,32]
  const float* b_span   = (const float*)d_in[4];  // [392]
  float* out = (float*)d_out;                     // [4,128,64,64]

  float* red   = (float*)d_ws;                    // 4*32*4096      = 2 MB
  float* x_pad = red + 4 * NR * HW;               // 4*128*76*80    = 12.5 MB
  float* ker   = x_pad + (size_t)4 * NC * PR * PC;// 4*8*49*4096    = 25.7 MB

  zero_pad<<<512, 256, 0, stream>>>(x_pad);
  red_gen<<<256, 256, 0, stream>>>(x, w_reduce, b_reduce, red, x_pad);
  ker_gen<<<3584, 256, 0, stream>>>(red, w_span, b_span, ker);
  inv_apply<<<2048, 256, 0, stream>>>(x_pad, ker, out);
}

// Round 7
// 106.901 us; speedup vs baseline: 1.3472x; 1.0091x over previous
//
#include <hip/hip_runtime.h>

// Inv2d: B=4, C=128, H=W=64, G=8 (16 ch/grp), K=7, dil=2, pad=6,
// reduce 128->32, span 32->392.
//
// Round 7: R6 revealed the harness's 256MB d_ws 0xAA-fill (45us @ 6TB/s,
// top-5 all fillBuffer) is the fixed floor; our kernels ~50us. Levers:
//  - float2-paired fp32 FMA (aim: v_pk_fma_f32, 2 FMA/inst) in ker_gen
//    (2 px/thread) and inv_apply -> halves the 10.4us FMA-issue floor.
//  - inv_apply: thread = 1ch x 8px, block = 2 rows; kv slice in LDS with
//    row-stride 68 (bank-alias-free); x window shared across the 8 px.
//  - zero_pad merged into red_gen (3 launches, not 4).

#define HW 4096   // 64*64
#define NC 128
#define NR 32
#define KK 49
#define PR 76     // padded rows (6+64+6)
#define PC 80     // padded cols (8+64+8, float4-aligned)
#define KSTR 136  // LDS per-tap stride (2 rows x 68); 68 breaks bank alias

// ---------------------------------------------------------------- red_gen
__global__ __launch_bounds__(256) void red_gen(
    const float* __restrict__ x, const float* __restrict__ w_reduce,
    const float* __restrict__ b_reduce, float* __restrict__ red,
    float* __restrict__ x_pad) {
  // grid: 256 = b(4) x row(64). Block: one 64-px row, all 32 outputs.
  // Also writes x_pad interior row + this block's share of border zeros.
  __shared__ float xs[NC][64];       // 32 KB
  int t = threadIdx.x;
  int blk = blockIdx.x;
  int b = blk >> 6;
  int row = blk & 63;
  int p0 = row * 64;

  // ---- border zeroing: 992 of batch-b's 63488 border float4s ----
  {
    float4 z = make_float4(0.f, 0.f, 0.f, 0.f);
    float* xpb0 = x_pad + (size_t)b * NC * PR * PC;
#pragma unroll
    for (int it = 0; it < 4; ++it) {
      int local = it * 256 + t;
      if (local < 992) {
        int f = row * 992 + local;       // 0..63487
        int plane = f / 496;
        int k = f - plane * 496;
        int d;
        if (k < 120) d = k;                       // rows 0..5 (all 20 f4)
        else if (k < 240) d = k - 120 + 70 * 20;  // rows 70..75
        else {
          int k2 = k - 240;                       // rows 6..69, side cols
          int rr = 6 + (k2 >> 2);
          int c4 = k2 & 3;                        // f4 col 0,1,18,19
          d = rr * 20 + ((c4 < 2) ? c4 : 16 + c4);
        }
        *(float4*)(xpb0 + (size_t)plane * PR * PC + d * 4) = z;
      }
    }
  }

  const float* xb = x + b * NC * HW + p0;
  float* xpb = x_pad + ((size_t)(b * NC) * PR + (row + 6)) * PC + 8;
  int fx = t & 15;
  int c0 = t >> 4;
#pragma unroll
  for (int r = 0; r < 8; ++r) {
    int c = c0 + 16 * r;
    float4 v = *(const float4*)(xb + c * HW + fx * 4);
    *(float4*)(&xs[c][fx * 4]) = v;
    *(float4*)(xpb + (size_t)c * PR * PC + fx * 4) = v;  // x_pad interior
  }
  __syncthreads();

  int px = t & 63;
  int quad = __builtin_amdgcn_readfirstlane(t >> 6);  // wave-uniform octet
  const float* wq = w_reduce + quad * 8 * NC;         // scalar (s_load) base

  float acc[8];
#pragma unroll
  for (int j = 0; j < 8; ++j) acc[j] = b_reduce[quad * 8 + j];

#pragma unroll 8
  for (int k = 0; k < NC; ++k) {
    float xk = xs[k][px];
#pragma unroll
    for (int j = 0; j < 8; ++j) acc[j] += xk * wq[j * NC + k];
  }

  float* rp = red + (b * NR + quad * 8) * HW + p0 + px;
#pragma unroll
  for (int j = 0; j < 8; ++j) rp[j * HW] = acc[j];
}

// ---------------------------------------------------------------- ker_gen
__global__ __launch_bounds__(256) void ker_gen(
    const float* __restrict__ red, const float* __restrict__ w_span,
    const float* __restrict__ b_span, float* __restrict__ ker) {
  // grid: 1792 = pchunk(8) x i(7) x g(8) x b(4); thread: 7 taps, 2 px
  int blk = blockIdx.x;
  int pchunk = blk & 7;
  int t1 = blk >> 3;
  int i = t1 % 7;
  int t2 = t1 / 7;
  int g = t2 & 7;
  int b = t2 >> 3;
  int p = pchunk * 512 + threadIdx.x * 2;

  float2 r[NR];
  const float* rp = red + b * NR * HW + p;
#pragma unroll
  for (int o = 0; o < NR; ++o) r[o] = *(const float2*)(rp + o * HW);

  float* kp = ker + ((size_t)((b * 8 + g) * KK + i * 7)) * HW + p;
#pragma unroll
  for (int j = 0; j < 7; ++j) {
    const float* wrow = w_span + (g * KK + i * 7 + j) * NR;  // s_load
    float bs = b_span[g * KK + i * 7 + j];
    // paired independent FMAs -> v_pk_fma_f32 candidates
    float sx = bs, sy = bs, tx = 0.f, ty = 0.f;
#pragma unroll
    for (int o = 0; o < NR; o += 2) {
      float w0 = wrow[o], w1 = wrow[o + 1];
      sx = fmaf(r[o].x, w0, sx);
      sy = fmaf(r[o].y, w0, sy);
      tx = fmaf(r[o + 1].x, w1, tx);
      ty = fmaf(r[o + 1].y, w1, ty);
    }
    *(float2*)(kp + j * HW) = make_float2(sx + tx, sy + ty);
  }
}

// ---------------------------------------------------------------- inv_apply
__global__ __launch_bounds__(256) void inv_apply(
    const float* __restrict__ x_pad, const float* __restrict__ ker,
    float* __restrict__ out) {
  // grid: 1024 = hpair(32) x g(8) x b(4)
  // block: 256 thr = 16 ch x 2 rows x 8 col-octets; thread = 1 ch, 8 px
  __shared__ float kvs[KK * KSTR];   // 26.7 KB
  int blk = blockIdx.x;
  int hp = blk & 31;
  int g = (blk >> 5) & 7;
  int b = blk >> 8;
  int tid = threadIdx.x;
  int h0 = hp * 2;

  // stage ker[b,g,:, rows h0..h0+1] -> LDS (rows contiguous: 128-float runs)
  const float* kerbg = ker + ((size_t)(b * 8 + g) * KK) * HW + h0 * 64;
#pragma unroll
  for (int it = 0; it < 7; ++it) {
    int idx4 = it * 256 + tid;
    if (idx4 < KK * 32) {
      int tp = idx4 >> 5;            // tap
      int rem = idx4 & 31;           // r*16 + c4
      int r = rem >> 4, c4 = rem & 15;
      float4 v = *(const float4*)(kerbg + (size_t)tp * HW + rem * 4);
      *(float4*)(&kvs[tp * KSTR + r * 68 + c4 * 4]) = v;
    }
  }
  __syncthreads();

  int c = tid >> 4;                  // channel in group
  int sub = tid & 15;
  int r = sub >> 3;                  // row 0..1
  int oct = sub & 7;                 // col octet
  int h = h0 + r;

  const float* xrow =
      x_pad + ((size_t)(b * NC + g * 16 + c) * PR + h) * PC + 8 * oct;
  float2 a0 = {0.f, 0.f}, a1 = {0.f, 0.f}, a2 = {0.f, 0.f}, a3 = {0.f, 0.f};

#pragma unroll
  for (int i = 0; i < 7; ++i) {
    const float* pr = xrow + 2 * i * PC;
    float xr[24];
#pragma unroll
    for (int m = 0; m < 6; ++m) {
      float4 v = *(const float4*)(pr + 4 * m);
      xr[4 * m] = v.x; xr[4 * m + 1] = v.y;
      xr[4 * m + 2] = v.z; xr[4 * m + 3] = v.w;
    }
#pragma unroll
    for (int j = 0; j < 7; ++j) {
      const float* kb = &kvs[(i * 7 + j) * KSTR + r * 68 + 8 * oct];
      float4 k0 = *(const float4*)(kb);
      float4 k1 = *(const float4*)(kb + 4);
      // px k uses x index 2+2j+k; paired px -> pk-FMA candidates
      a0.x = fmaf(xr[2 + 2 * j], k0.x, a0.x);
      a0.y = fmaf(xr[3 + 2 * j], k0.y, a0.y);
      a1.x = fmaf(xr[4 + 2 * j], k0.z, a1.x);
      a1.y = fmaf(xr[5 + 2 * j], k0.w, a1.y);
      a2.x = fmaf(xr[6 + 2 * j], k1.x, a2.x);
      a2.y = fmaf(xr[7 + 2 * j], k1.y, a2.y);
      a3.x = fmaf(xr[8 + 2 * j], k1.z, a3.x);
      a3.y = fmaf(xr[9 + 2 * j], k1.w, a3.y);
    }
  }

  float* op = out + (size_t)(b * NC + g * 16 + c) * HW + h * 64 + 8 * oct;
  *(float4*)op = make_float4(a0.x, a0.y, a1.x, a1.y);
  *(float4*)(op + 4) = make_float4(a2.x, a2.y, a3.x, a3.y);
}

extern "C" void kernel_launch(void* const* d_in, const int* in_sizes, int n_in,
                              void* d_out, int out_size, void* d_ws, size_t ws_size,
                              hipStream_t stream) {
  const float* x        = (const float*)d_in[0];  // [4,128,64,64]
  const float* w_reduce = (const float*)d_in[1];  // [32,128]
  const float* b_reduce = (const float*)d_in[2];  // [32]
  const float* w_span   = (const float*)d_in[3];  // [392,32]
  const float* b_span   = (const float*)d_in[4];  // [392]
  float* out = (float*)d_out;                     // [4,128,64,64]

  float* red   = (float*)d_ws;                    // 4*32*4096      = 2 MB
  float* x_pad = red + 4 * NR * HW;               // 4*128*76*80    = 12.5 MB
  float* ker   = x_pad + (size_t)4 * NC * PR * PC;// 4*8*49*4096    = 25.7 MB

  red_gen<<<256, 256, 0, stream>>>(x, w_reduce, b_reduce, red, x_pad);
  ker_gen<<<1792, 256, 0, stream>>>(red, w_span, b_span, ker);
  inv_apply<<<1024, 256, 0, stream>>>(x_pad, ker, out);
}